// Round 6
// baseline (487.724 us; speedup 1.0000x reference)
//
#include <hip/hip_runtime.h>
#include <hip/hip_bf16.h>
#include <cmath>

#define NTOK 1728
#define DIMC 128
#define NHEAD 8
#define NB 4
#define TABN 12167
#define TSTRIDE 12168
#define NBLK 1024
#define SLDSW 6208   // u16 table-window entries (max needed 6111)

typedef __attribute__((ext_vector_type(8))) short bf16x8;
typedef __attribute__((ext_vector_type(4))) float f32x4;

static __device__ __forceinline__ unsigned short f2bf(float f) {
    union { float f; unsigned u; } v; v.f = f;
    unsigned r = v.u + 0x7fff + ((v.u >> 16) & 1);   // RNE
    return (unsigned short)(r >> 16);
}
static __device__ __forceinline__ int Pdec(int t) {
    return (t / 144) * 529 + ((t / 12) % 12) * 23 + (t % 12);
}

// device-scope grid barrier: 1024 blocks co-resident by construction
// (4 blocks/CU: LDS 32768*4 = 131072 <= 163840; VGPR <= 128 via launch_bounds)
static __device__ __forceinline__ void gridbar(unsigned* C, int id) {
    __syncthreads();
    if (threadIdx.x == 0) {
        __threadfence();                       // release
        atomicAdd(&C[id], 1u);
        while (__hip_atomic_load(&C[id], __ATOMIC_RELAXED,
                                 __HIP_MEMORY_SCOPE_AGENT) < (unsigned)NBLK)
            __builtin_amdgcn_s_sleep(2);
        __threadfence();                       // acquire
    }
    __syncthreads();
}

__global__ __launch_bounds__(256, 4) void k_mega(
    const float* __restrict__ x, const float* __restrict__ Wq,
    const float* __restrict__ Wk, const float* __restrict__ Wv,
    const float* __restrict__ Wp, const float* __restrict__ bp,
    const float* __restrict__ tbl,
    unsigned* C, float* n1, unsigned short* tblT,
    float* QS, float* Ko, float* Vo, unsigned short* EKVt,
    float* Yb, float* out)
{
    __shared__ __align__(16) unsigned char LDSU[32768];
    const int t = threadIdx.x;
    const int bid = (int)blockIdx.x;

    // ================= P1: q/k/v projections (864) | table prep (160) ======
    if (bid < 864) {
        float* xs = (float*)LDSU;              // [32][128] swizzled
        float* Ws = (float*)(LDSU + 16384);    // [32][128] weights / bounce
        const int rt = bid >> 2, cg = bid & 3;
        const int row0 = rt * 32;
        {
            const int cc = t & 31;
            #pragma unroll
            for (int p = 0; p < 4; ++p) {
                const int r = (t >> 5) + p * 8;
                float4 v = *(const float4*)&x[(size_t)(row0 + r) * DIMC + cc * 4];
                *(float4*)&xs[r * 128 + ((cc * 4) ^ ((r & 7) << 2))] = v;
            }
        }
        #pragma unroll 1
        for (int m = 0; m < 3; ++m) {
            const float* __restrict__ W = (m == 0) ? Wq : (m == 1) ? Wk : Wv;
            __syncthreads();                    // xs staged / prev bounce read
            {
                const int cc = t & 31;
                #pragma unroll
                for (int p = 0; p < 4; ++p) {
                    const int c = (t >> 5) + p * 8;
                    float4 v = *(const float4*)&W[(size_t)(cg * 32 + c) * DIMC + cc * 4];
                    *(float4*)&Ws[c * 128 + cc * 4] = v;
                }
            }
            __syncthreads();
            const int nl = t & 31, wx = t >> 5;
            float acc[4] = {0.f, 0.f, 0.f, 0.f};
            for (int k4 = 0; k4 < 32; ++k4) {
                const float4 xv = *(const float4*)&xs[nl * 128 + ((k4 * 4) ^ ((nl & 7) << 2))];
                #pragma unroll
                for (int c = 0; c < 4; ++c) {
                    const float4 wv = *(const float4*)&Ws[(wx * 4 + c) * 128 + k4 * 4];
                    acc[c] = fmaf(xv.x, wv.x, fmaf(xv.y, wv.y,
                             fmaf(xv.z, wv.z, fmaf(xv.w, wv.w, acc[c]))));
                }
            }
            if (m == 0) {
                #pragma unroll
                for (int c = 0; c < 4; ++c) acc[c] = 1.f / (1.f + expf(-acc[c]));
            }
            __syncthreads();                    // Ws reads done -> bounce
            #pragma unroll
            for (int c = 0; c < 4; ++c) Ws[nl * 33 + wx * 4 + c] = acc[c];
            __syncthreads();
            float* __restrict__ Out = (m == 0) ? QS : (m == 1) ? Ko : Vo;
            const int r = t >> 3, q = t & 7;
            float4 v;
            v.x = Ws[r * 33 + q * 4 + 0]; v.y = Ws[r * 33 + q * 4 + 1];
            v.z = Ws[r * 33 + q * 4 + 2]; v.w = Ws[r * 33 + q * 4 + 3];
            *(float4*)&Out[(size_t)(row0 + r) * DIMC + cg * 32 + q * 4] = v;
        }
    } else {
        // tblT[h][idx] = bf16(expm1(tbl[idx][h]))
        const int g0 = (bid - 864) * 640;
        for (int g = g0 + t; g < g0 + 640 && g < 8 * TABN; g += 256)
            tblT[(size_t)(g & 7) * TSTRIDE + (g >> 3)] = f2bf(expm1f(tbl[g]));
    }
    gridbar(C, 0);

    // ================= P2: EKVt bf16 [h][b*32+c][j] + n1 colsums ===========
    if (bid < 864) {
        const int b = bid & 3, jx = (bid >> 2) % 27, h = bid / 108;
        const int w = t >> 6, jj = t & 63;        // wave = d-quad, lane = j
        const int j = jx * 64 + jj;
        const size_t base = ((size_t)b * NTOK + j) * DIMC + h * 16 + w * 4;
        const float4 kv = *(const float4*)&Ko[base];
        const float4 vv = *(const float4*)&Vo[base];
        float nu[4], de[4];
        de[0] = expf(kv.x); de[1] = expf(kv.y);   // kmax/bmax cancel in num/den
        de[2] = expf(kv.z); de[3] = expf(kv.w);
        nu[0] = de[0] * vv.x; nu[1] = de[1] * vv.y;
        nu[2] = de[2] * vv.z; nu[3] = de[3] * vv.w;
        #pragma unroll
        for (int i = 0; i < 4; ++i) {
            EKVt[((size_t)h * DIMC + b * 32 + w * 4 + i) * NTOK + j] = f2bf(nu[i]);
            EKVt[((size_t)h * DIMC + b * 32 + 16 + w * 4 + i) * NTOK + j] = f2bf(de[i]);
        }
        #pragma unroll
        for (int s = 1; s < 64; s <<= 1) {
            #pragma unroll
            for (int i = 0; i < 4; ++i) {
                nu[i] += __shfl_xor(nu[i], s, 64);
                de[i] += __shfl_xor(de[i], s, 64);
            }
        }
        if (jj == 0) {
            #pragma unroll
            for (int i = 0; i < 4; ++i) {
                atomicAdd(&n1[(h * NB + b) * 32 + w * 4 + i], nu[i]);
                atomicAdd(&n1[(h * NB + b) * 32 + 16 + w * 4 + i], de[i]);
            }
        }
    }
    gridbar(C, 1);

    // ========== P3: MFMA einsum, i-tile 16, full j, inline finalize ========
    if (bid < 864) {
        unsigned short* slds = (unsigned short*)LDSU;               // table window
        unsigned short* alds = (unsigned short*)(LDSU + SLDSW * 2); // [16][64]
        unsigned short* blds = alds + 16 * 64;                      // [128][64]
        const int ti = bid % 108, h = bid / 108;
        const int i0 = ti * 16;
        const int albase = Pdec(i0) & ~7;       // window lo = P(i0) (16B aligned)
        {   // stage aligned vec8 window; valid gather idx always < row end
            const unsigned short* src = &tblT[(size_t)h * TSTRIDE + albase];
            const int nvec = (TSTRIDE - albase) >> 3;
            for (int s8 = t; s8 < (SLDSW >> 3); s8 += 256)
                if (s8 < nvec) *(bf16x8*)&slds[s8 * 8] = *(const bf16x8*)&src[s8 * 8];
        }
        const int w = t >> 6, l = t & 63;
        const int il = l & 15, kg = l >> 4;
        const int rr = w * 4;                   // A rows gathered by this thread
        int qb[4];
        #pragma unroll
        for (int r = 0; r < 4; ++r) qb[r] = Pdec(i0 + rr + r) + 6083 - albase;
        const int bc = t >> 3, bj8 = (t & 7) * 8;
        const int cf0 = w * 2;                  // wave w owns cf {2w,2w+1} = batch w
        f32x4 acc0 = {0.f, 0.f, 0.f, 0.f}, acc1 = {0.f, 0.f, 0.f, 0.f};

        #pragma unroll 1
        for (int jt = 0; jt < 27; ++jt) {
            const int j0 = jt * 64;
            const int pj = Pdec(j0 + l);
            __syncthreads();
            #pragma unroll
            for (int p = 0; p < 4; ++p) {       // B: EKVt[h][c][j0..+64] swizzled
                const int c = bc + p * 32;
                bf16x8 v = *(const bf16x8*)&EKVt[((size_t)h * DIMC + c) * NTOK + j0 + bj8];
                *(bf16x8*)&blds[c * 64 + (bj8 ^ ((c & 7) << 3))] = v;
            }
            #pragma unroll
            for (int r = 0; r < 4; ++r) {       // A: w' from LDS table window
                const int row = rr + r;
                alds[row * 64 + (l ^ ((row & 7) << 3))] = slds[qb[r] - pj];
            }
            __syncthreads();
            #pragma unroll
            for (int kk = 0; kk < 2; ++kk) {
                const int ka = kk * 32 + kg * 8;
                bf16x8 af = *(const bf16x8*)&alds[il * 64 + (ka ^ ((il & 7) << 3))];
                bf16x8 b0 = *(const bf16x8*)&blds[(cf0 * 16 + il) * 64 + (ka ^ ((il & 7) << 3))];
                acc0 = __builtin_amdgcn_mfma_f32_16x16x32_bf16(af, b0, acc0, 0, 0, 0);
                bf16x8 b1 = *(const bf16x8*)&blds[((cf0 + 1) * 16 + il) * 64 + (ka ^ ((il & 7) << 3))];
                acc1 = __builtin_amdgcn_mfma_f32_16x16x32_bf16(af, b1, acc1, 0, 0, 0);
            }
        }
        // finalize: wave = batch, d = il; D rows = kg*4+r
        const float nn0 = n1[(h * NB + w) * 32 + il];
        const float dd0 = n1[(h * NB + w) * 32 + 16 + il];
        #pragma unroll
        for (int r = 0; r < 4; ++r) {
            const int i = i0 + kg * 4 + r;
            const size_t off = ((size_t)w * NTOK + i) * DIMC + h * 16 + il;
            Yb[off] = QS[off] * (nn0 + acc0[r]) / (dd0 + acc1[r]);
        }
    }
    gridbar(C, 2);

    // ================= P4: out = Y @ Wp^T + bp =================
    if (bid < 864) {
        float* xs = (float*)LDSU;
        float* Ws = (float*)(LDSU + 16384);
        const int rt = bid >> 2, cg = bid & 3;
        const int row0 = rt * 32;
        {
            const int cc = t & 31;
            #pragma unroll
            for (int p = 0; p < 4; ++p) {
                const int r = (t >> 5) + p * 8;
                float4 v = *(const float4*)&Yb[(size_t)(row0 + r) * DIMC + cc * 4];
                *(float4*)&xs[r * 128 + ((cc * 4) ^ ((r & 7) << 2))] = v;
            }
            #pragma unroll
            for (int p = 0; p < 4; ++p) {
                const int c = (t >> 5) + p * 8;
                float4 v = *(const float4*)&Wp[(size_t)(cg * 32 + c) * DIMC + cc * 4];
                *(float4*)&Ws[c * 128 + cc * 4] = v;
            }
        }
        __syncthreads();
        const int nl = t & 31, wx = t >> 5;
        float acc[4] = {0.f, 0.f, 0.f, 0.f};
        for (int k4 = 0; k4 < 32; ++k4) {
            const float4 xv = *(const float4*)&xs[nl * 128 + ((k4 * 4) ^ ((nl & 7) << 2))];
            #pragma unroll
            for (int c = 0; c < 4; ++c) {
                const float4 wv = *(const float4*)&Ws[(wx * 4 + c) * 128 + k4 * 4];
                acc[c] = fmaf(xv.x, wv.x, fmaf(xv.y, wv.y,
                         fmaf(xv.z, wv.z, fmaf(xv.w, wv.w, acc[c]))));
            }
        }
        #pragma unroll
        for (int c = 0; c < 4; ++c) acc[c] += bp[cg * 32 + wx * 4 + c];
        __syncthreads();
        #pragma unroll
        for (int c = 0; c < 4; ++c) Ws[nl * 33 + wx * 4 + c] = acc[c];
        __syncthreads();
        const int r = t >> 3, q = t & 7;
        float4 v;
        v.x = Ws[r * 33 + q * 4 + 0]; v.y = Ws[r * 33 + q * 4 + 1];
        v.z = Ws[r * 33 + q * 4 + 2]; v.w = Ws[r * 33 + q * 4 + 3];
        *(float4*)&out[(size_t)(row0 + r) * DIMC + cg * 32 + q * 4] = v;
    }
}

extern "C" void kernel_launch(void* const* d_in, const int* in_sizes, int n_in,
                              void* d_out, int out_size, void* d_ws, size_t ws_size,
                              hipStream_t stream) {
    const float* x    = (const float*)d_in[0];
    const float* Wq   = (const float*)d_in[1];
    const float* Wk   = (const float*)d_in[2];
    const float* Wv   = (const float*)d_in[3];
    const float* Wp   = (const float*)d_in[4];
    const float* bp   = (const float*)d_in[5];
    const float* tbl  = (const float*)d_in[6];

    float* ws = (float*)d_ws;
    unsigned* C = (unsigned*)ws;                                // 16 u32
    float* n1 = ws + 16;                                        // 1024 f32
    unsigned short* tblT = (unsigned short*)(ws + 16 + 1024);   // 97344 u16
    float* QS = ws + 16 + 1024 + 48672;
    float* Ko = QS + 884736;
    float* Vo = Ko + 884736;
    unsigned short* EKVt = (unsigned short*)(Vo + 884736);      // 1769472 u16
    float* Yb = Vo + 884736 + 884736;

    hipMemsetAsync(ws, 0, (16 + 1024) * sizeof(float), stream);
    k_mega<<<dim3(NBLK), 256, 0, stream>>>(x, Wq, Wk, Wv, Wp, bp, tbl,
                                           C, n1, tblT, QS, Ko, Vo, EKVt, Yb,
                                           (float*)d_out);
}

// Round 7
// 315.201 us; speedup vs baseline: 1.5473x; 1.5473x over previous
//
#include <hip/hip_runtime.h>
#include <hip/hip_bf16.h>
#include <cmath>

#define NTOK 1728
#define DIMC 128
#define NHEAD 8
#define NB 4
#define TABN 12167
#define TSTRIDE 12168
#define SLDSW 6208   // u16 table-window entries (max needed 6128, staged exactly to row end)

typedef __attribute__((ext_vector_type(8))) short bf16x8;
typedef __attribute__((ext_vector_type(4))) float f32x4;

static __device__ __forceinline__ unsigned short f2bf(float f) {
    union { float f; unsigned u; } v; v.f = f;
    unsigned r = v.u + 0x7fff + ((v.u >> 16) & 1);   // RNE
    return (unsigned short)(r >> 16);
}
static __device__ __forceinline__ int Pdec(int t) {
    return (t / 144) * 529 + ((t / 12) % 12) * 23 + (t % 12);
}

// ===== Kernel A: q/k/v proj + EKVt + n1 (864) | table prep (160) ============
__global__ __launch_bounds__(256, 4) void k_proj_ekv(
    const float* __restrict__ x, const float* __restrict__ Wq,
    const float* __restrict__ Wk, const float* __restrict__ Wv,
    const float* __restrict__ tbl,
    unsigned short* __restrict__ tblT, float* __restrict__ n1,
    float* __restrict__ QS, unsigned short* __restrict__ EKVt)
{
    __shared__ __align__(16) float xs[32 * 128];
    __shared__ __align__(16) float Ws[32 * 128];
    const int t = threadIdx.x;
    const int bid = (int)blockIdx.x;
    if (bid >= 864) {     // tblT[h][idx] = bf16(expm1(tbl[idx][h]))
        const int g0 = (bid - 864) * 640;
        for (int g = g0 + t; g < g0 + 640 && g < 8 * TABN; g += 256)
            tblT[(size_t)(g & 7) * TSTRIDE + (g >> 3)] = f2bf(expm1f(tbl[g]));
        return;
    }
    const int rt = bid >> 2, cg = bid & 3;
    const int row0 = rt * 32;
    {   // stage x tile, XOR-swizzled 16B units
        const int cc = t & 31;
        #pragma unroll
        for (int p = 0; p < 4; ++p) {
            const int r = (t >> 5) + p * 8;
            float4 v = *(const float4*)&x[(size_t)(row0 + r) * DIMC + cc * 4];
            *(float4*)&xs[r * 128 + ((cc * 4) ^ ((r & 7) << 2))] = v;
        }
    }
    // thread tile: rows {tr, tr+16}, group-cols {tc, tc+16}; tr = t>>4, tc = t&15
    const int tr = t >> 4, tc = t & 15;
    float kreg[2][2], vreg[2][2];
    #pragma unroll 1
    for (int m = 0; m < 3; ++m) {
        const float* __restrict__ W = (m == 0) ? Wq : (m == 1) ? Wk : Wv;
        __syncthreads();                    // xs ready / prev Ws reads done
        {   // stage W slice [32 cols][128 k], swizzled like xs
            const int cc = t & 31;
            #pragma unroll
            for (int p = 0; p < 4; ++p) {
                const int c = (t >> 5) + p * 8;
                float4 v = *(const float4*)&W[(size_t)(cg * 32 + c) * DIMC + cc * 4];
                *(float4*)&Ws[c * 128 + ((cc * 4) ^ ((c & 7) << 2))] = v;
            }
        }
        __syncthreads();
        float acc[2][2] = {{0.f, 0.f}, {0.f, 0.f}};
        #pragma unroll 4
        for (int k4 = 0; k4 < 32; ++k4) {
            float4 xv[2], wv[2];
            #pragma unroll
            for (int rr = 0; rr < 2; ++rr) {
                const int row = tr + 16 * rr;
                xv[rr] = *(const float4*)&xs[row * 128 + ((k4 * 4) ^ ((row & 7) << 2))];
            }
            #pragma unroll
            for (int cc = 0; cc < 2; ++cc) {
                const int c = tc + 16 * cc;
                wv[cc] = *(const float4*)&Ws[c * 128 + ((k4 * 4) ^ ((c & 7) << 2))];
            }
            #pragma unroll
            for (int rr = 0; rr < 2; ++rr)
                #pragma unroll
                for (int cc = 0; cc < 2; ++cc)
                    acc[rr][cc] = fmaf(xv[rr].x, wv[cc].x, fmaf(xv[rr].y, wv[cc].y,
                                  fmaf(xv[rr].z, wv[cc].z, fmaf(xv[rr].w, wv[cc].w, acc[rr][cc]))));
        }
        if (m == 0) {
            #pragma unroll
            for (int rr = 0; rr < 2; ++rr)
                #pragma unroll
                for (int cc = 0; cc < 2; ++cc)
                    acc[rr][cc] = 1.f / (1.f + expf(-acc[rr][cc]));
            __syncthreads();                // Ws reads done -> bounce
            #pragma unroll
            for (int rr = 0; rr < 2; ++rr)
                #pragma unroll
                for (int cc = 0; cc < 2; ++cc)
                    Ws[(tr + 16 * rr) * 33 + tc + 16 * cc] = acc[rr][cc];
            __syncthreads();
            const int r = t >> 3, q = t & 7;
            float4 v;
            v.x = Ws[r * 33 + q * 4 + 0]; v.y = Ws[r * 33 + q * 4 + 1];
            v.z = Ws[r * 33 + q * 4 + 2]; v.w = Ws[r * 33 + q * 4 + 3];
            *(float4*)&QS[(size_t)(row0 + r) * DIMC + cg * 32 + q * 4] = v;
        } else if (m == 1) {
            #pragma unroll
            for (int rr = 0; rr < 2; ++rr) { kreg[rr][0] = acc[rr][0]; kreg[rr][1] = acc[rr][1]; }
        } else {
            #pragma unroll
            for (int rr = 0; rr < 2; ++rr) { vreg[rr][0] = acc[rr][0]; vreg[rr][1] = acc[rr][1]; }
        }
    }
    // EKV transform in registers: e = exp(k) (kmax/bmax cancel in num/den)
    const int b = row0 / NTOK;
    const int j0r = row0 - b * NTOK;
    float nu[2], de[2];                     // per cc, summed over rr
    #pragma unroll
    for (int cc = 0; cc < 2; ++cc) { nu[cc] = 0.f; de[cc] = 0.f; }
    #pragma unroll
    for (int rr = 0; rr < 2; ++rr) {
        const int j = j0r + tr + 16 * rr;
        #pragma unroll
        for (int cc = 0; cc < 2; ++cc) {
            const int h = cg * 2 + cc;      // col = cg*32 + tc + 16*cc -> h, d=tc
            const float e = expf(kreg[rr][cc]);
            const float nn = e * vreg[rr][cc];
            EKVt[((size_t)(h * DIMC + b * 32 + tc)) * NTOK + j] = f2bf(nn);
            EKVt[((size_t)(h * DIMC + b * 32 + 16 + tc)) * NTOK + j] = f2bf(e);
            nu[cc] += nn; de[cc] += e;
        }
    }
    #pragma unroll
    for (int s = 16; s <= 32; s <<= 1) {    // reduce over tr within wave
        #pragma unroll
        for (int cc = 0; cc < 2; ++cc) {
            nu[cc] += __shfl_xor(nu[cc], s, 64);
            de[cc] += __shfl_xor(de[cc], s, 64);
        }
    }
    if ((t & 48) == 0) {                    // 16 lanes/wave hold 8-row partials
        #pragma unroll
        for (int cc = 0; cc < 2; ++cc) {
            const int h = cg * 2 + cc;
            atomicAdd(&n1[(h * NB + b) * 32 + tc], nu[cc]);
            atomicAdd(&n1[(h * NB + b) * 32 + 16 + tc], de[cc]);
        }
    }
}

// ===== Kernel C: MFMA einsum (B direct from global) + finalize + last-block proj
__global__ __launch_bounds__(256, 4) void k_aft_out(
    const unsigned short* __restrict__ tblT,
    const unsigned short* __restrict__ EKVt,
    const float* __restrict__ n1, const float* __restrict__ QS,
    const float* __restrict__ Wp, const float* __restrict__ bp,
    float* __restrict__ Yb, float* __restrict__ out, unsigned* __restrict__ cnt)
{
    __shared__ __align__(16) unsigned char LDSU[33280];
    __shared__ unsigned elect;
    unsigned short* slds = (unsigned short*)LDSU;            // 12416 B window
    unsigned short* alds = (unsigned short*)(LDSU + 12544);  // [16][64] w' tile
    const int t = threadIdx.x;
    const int ti = (int)blockIdx.x % 108, h = (int)blockIdx.x / 108;
    const int i0 = ti * 16;
    const int albase = Pdec(i0) & ~7;
    {   // stage table window (aligned vec8, exact to row end)
        const unsigned short* src = &tblT[(size_t)h * TSTRIDE + albase];
        const int nvec = (TSTRIDE - albase) >> 3;
        for (int s8 = t; s8 < (SLDSW >> 3); s8 += 256)
            if (s8 < nvec) *(bf16x8*)&slds[s8 * 8] = *(const bf16x8*)&src[s8 * 8];
    }
    const int w = t >> 6, l = t & 63;       // wave = batch b
    const int il = l & 15, kg = l >> 4;
    int qb[4];
    #pragma unroll
    for (int r = 0; r < 4; ++r) qb[r] = Pdec(i0 + w * 4 + r) + 6083 - albase;
    // B fragment pointers: 8 consecutive j = one 16B load, direct to MFMA regs
    const unsigned short* Bp0 = &EKVt[(size_t)(h * DIMC + w * 32 + il) * NTOK + kg * 8];
    const unsigned short* Bp1 = Bp0 + (size_t)16 * NTOK;
    f32x4 acc0 = {0.f, 0.f, 0.f, 0.f}, acc1 = {0.f, 0.f, 0.f, 0.f};
    bf16x8 Bc0 = *(const bf16x8*)&Bp0[0],  Bc1 = *(const bf16x8*)&Bp1[0];
    bf16x8 Bc2 = *(const bf16x8*)&Bp0[32], Bc3 = *(const bf16x8*)&Bp1[32];

    #pragma unroll 1
    for (int jt = 0; jt < 27; ++jt) {
        const int j0 = jt * 64;
        const int pj = Pdec(j0 + l);
        __syncthreads();                    // alds reuse safe
        #pragma unroll
        for (int r = 0; r < 4; ++r) {       // A: gather w' from LDS window
            const int row = w * 4 + r;
            alds[row * 64 + (l ^ ((row & 7) << 3))] = slds[qb[r] - pj];
        }
        const int j0n = (jt < 26) ? j0 + 64 : 0;   // prefetch next B tile
        bf16x8 Bn0 = *(const bf16x8*)&Bp0[j0n],      Bn1 = *(const bf16x8*)&Bp1[j0n];
        bf16x8 Bn2 = *(const bf16x8*)&Bp0[j0n + 32], Bn3 = *(const bf16x8*)&Bp1[j0n + 32];
        __syncthreads();
        bf16x8 af0 = *(const bf16x8*)&alds[il * 64 + ((kg * 8) ^ ((il & 7) << 3))];
        bf16x8 af1 = *(const bf16x8*)&alds[il * 64 + ((32 + kg * 8) ^ ((il & 7) << 3))];
        acc0 = __builtin_amdgcn_mfma_f32_16x16x32_bf16(af0, Bc0, acc0, 0, 0, 0);
        acc1 = __builtin_amdgcn_mfma_f32_16x16x32_bf16(af0, Bc1, acc1, 0, 0, 0);
        acc0 = __builtin_amdgcn_mfma_f32_16x16x32_bf16(af1, Bc2, acc0, 0, 0, 0);
        acc1 = __builtin_amdgcn_mfma_f32_16x16x32_bf16(af1, Bc3, acc1, 0, 0, 0);
        Bc0 = Bn0; Bc1 = Bn1; Bc2 = Bn2; Bc3 = Bn3;
    }
    // finalize y = sigmoid(q) * (n1 + num) / (n1d + den); wave = batch, d = il
    const float nn0 = n1[(h * NB + w) * 32 + il];
    const float dd0 = n1[(h * NB + w) * 32 + 16 + il];
    #pragma unroll
    for (int r = 0; r < 4; ++r) {
        const int i = i0 + kg * 4 + r;
        const size_t off = ((size_t)w * NTOK + i) * DIMC + h * 16 + il;
        Yb[off] = QS[off] * (nn0 + acc0[r]) / (dd0 + acc1[r]);
    }
    // ---- last-block election per i-tile: winner projects 64 finished rows --
    __threadfence();                        // release Yb writes device-wide
    __syncthreads();
    if (t == 0) elect = atomicAdd(&cnt[ti], 1u);
    __syncthreads();
    if (elect != 7u) return;
    __threadfence();                        // acquire: invalidate stale caches
    __syncthreads();
    float* ys = (float*)LDSU;               // [64][129] overlay (slds dead now)
    {
        const int cc = t & 31;
        #pragma unroll
        for (int p = 0; p < 8; ++p) {
            const int rr = (t >> 5) + p * 8;
            const int bb = rr >> 4, ii = i0 + (rr & 15);
            float4 v = *(const float4*)&Yb[((size_t)bb * NTOK + ii) * DIMC + cc * 4];
            *(float4*)&ys[rr * 129 + cc * 4] = v;
        }
    }
    __syncthreads();
    const int nl = t & 63, wx2 = t >> 6;    // row = nl, cols wx2*32..+32
    float po[32];
    #pragma unroll
    for (int c = 0; c < 32; ++c) po[c] = 0.f;
    for (int k4 = 0; k4 < 32; ++k4) {
        const float4 xv = *(const float4*)&ys[nl * 129 + k4 * 4];
        #pragma unroll
        for (int c = 0; c < 32; ++c) {
            const float4 wv = *(const float4*)&Wp[(size_t)(wx2 * 32 + c) * DIMC + k4 * 4];
            po[c] = fmaf(xv.x, wv.x, fmaf(xv.y, wv.y,
                    fmaf(xv.z, wv.z, fmaf(xv.w, wv.w, po[c]))));
        }
    }
    const int bb = nl >> 4, ii = i0 + (nl & 15);
    const size_t ob = ((size_t)bb * NTOK + ii) * DIMC + wx2 * 32;
    #pragma unroll
    for (int c4 = 0; c4 < 8; ++c4) {
        float4 v;
        v.x = po[c4 * 4 + 0] + bp[wx2 * 32 + c4 * 4 + 0];
        v.y = po[c4 * 4 + 1] + bp[wx2 * 32 + c4 * 4 + 1];
        v.z = po[c4 * 4 + 2] + bp[wx2 * 32 + c4 * 4 + 2];
        v.w = po[c4 * 4 + 3] + bp[wx2 * 32 + c4 * 4 + 3];
        *(float4*)&out[ob + c4 * 4] = v;
    }
}

extern "C" void kernel_launch(void* const* d_in, const int* in_sizes, int n_in,
                              void* d_out, int out_size, void* d_ws, size_t ws_size,
                              hipStream_t stream) {
    const float* x    = (const float*)d_in[0];
    const float* Wq   = (const float*)d_in[1];
    const float* Wk   = (const float*)d_in[2];
    const float* Wv   = (const float*)d_in[3];
    const float* Wp   = (const float*)d_in[4];
    const float* bp   = (const float*)d_in[5];
    const float* tbl  = (const float*)d_in[6];

    float* ws = (float*)d_ws;
    unsigned* cnt = (unsigned*)ws;                              // 128 u32
    float* n1 = ws + 128;                                       // 1024 f32
    unsigned short* tblT = (unsigned short*)(ws + 128 + 1024);  // 97344 u16
    float* QS = ws + 128 + 1024 + 48672;                        // 884736 f32
    unsigned short* EKVt = (unsigned short*)(QS + 884736);      // 1769472 u16
    float* Yb = QS + 884736 + 884736;                           // 884736 f32

    hipMemsetAsync(ws, 0, (128 + 1024) * sizeof(float), stream);  // cnt + n1
    k_proj_ekv<<<dim3(1024), 256, 0, stream>>>(x, Wq, Wk, Wv, tbl, tblT, n1, QS, EKVt);
    k_aft_out<<<dim3(864), 256, 0, stream>>>(tblT, EKVt, n1, QS, Wp, bp,
                                             Yb, (float*)d_out, cnt);
}

// Round 8
// 154.299 us; speedup vs baseline: 3.1609x; 2.0428x over previous
//
#include <hip/hip_runtime.h>
#include <hip/hip_bf16.h>
#include <cmath>

#define NTOK 1728
#define DIMC 128
#define NHEAD 8
#define NB 4
#define TABN 12167
#define TSTRIDE 12168

typedef __attribute__((ext_vector_type(8))) short bf16x8;
typedef __attribute__((ext_vector_type(4))) float f32x4;

static __device__ __forceinline__ unsigned short f2bf(float f) {
    union { float f; unsigned u; } v; v.f = f;
    unsigned r = v.u + 0x7fff + ((v.u >> 16) & 1);   // RNE
    return (unsigned short)(r >> 16);
}
static __device__ __forceinline__ int Pdec(int t) {
    return (t / 144) * 529 + ((t / 12) % 12) * 23 + (t % 12);
}

// ===== Kernel A: q/k/v proj + EKVt + n1 (864) | table prep (160) ============
__global__ __launch_bounds__(256, 4) void k_proj_ekv(
    const float* __restrict__ x, const float* __restrict__ Wq,
    const float* __restrict__ Wk, const float* __restrict__ Wv,
    const float* __restrict__ tbl,
    unsigned short* __restrict__ tblT, float* __restrict__ n1,
    float* __restrict__ QS, unsigned short* __restrict__ EKVt)
{
    __shared__ __align__(16) float xs[32 * 128];
    __shared__ __align__(16) float Ws[32 * 128];
    const int t = threadIdx.x;
    const int bid = (int)blockIdx.x;
    if (bid >= 864) {     // tblT[h][idx] = bf16(expm1(tbl[idx][h]))
        const int g0 = (bid - 864) * 640;
        for (int g = g0 + t; g < g0 + 640 && g < 8 * TABN; g += 256)
            tblT[(size_t)(g & 7) * TSTRIDE + (g >> 3)] = f2bf(expm1f(tbl[g]));
        return;
    }
    const int rt = bid >> 2, cg = bid & 3;
    const int row0 = rt * 32;
    {   // stage x tile, XOR-swizzled 16B units
        const int cc = t & 31;
        #pragma unroll
        for (int p = 0; p < 4; ++p) {
            const int r = (t >> 5) + p * 8;
            float4 v = *(const float4*)&x[(size_t)(row0 + r) * DIMC + cc * 4];
            *(float4*)&xs[r * 128 + ((cc * 4) ^ ((r & 7) << 2))] = v;
        }
    }
    // thread tile: rows {tr, tr+16}, group-cols {tc, tc+16}
    const int tr = t >> 4, tc = t & 15;
    float kreg[2][2], vreg[2][2];
    #pragma unroll 1
    for (int m = 0; m < 3; ++m) {
        const float* __restrict__ W = (m == 0) ? Wq : (m == 1) ? Wk : Wv;
        __syncthreads();                    // xs ready / prev Ws reads done
        {   // stage W slice [32 cols][128 k], swizzled
            const int cc = t & 31;
            #pragma unroll
            for (int p = 0; p < 4; ++p) {
                const int c = (t >> 5) + p * 8;
                float4 v = *(const float4*)&W[(size_t)(cg * 32 + c) * DIMC + cc * 4];
                *(float4*)&Ws[c * 128 + ((cc * 4) ^ ((c & 7) << 2))] = v;
            }
        }
        __syncthreads();
        float acc[2][2] = {{0.f, 0.f}, {0.f, 0.f}};
        #pragma unroll 4
        for (int k4 = 0; k4 < 32; ++k4) {
            float4 xv[2], wv[2];
            #pragma unroll
            for (int rr = 0; rr < 2; ++rr) {
                const int row = tr + 16 * rr;
                xv[rr] = *(const float4*)&xs[row * 128 + ((k4 * 4) ^ ((row & 7) << 2))];
            }
            #pragma unroll
            for (int cc = 0; cc < 2; ++cc) {
                const int c = tc + 16 * cc;
                wv[cc] = *(const float4*)&Ws[c * 128 + ((k4 * 4) ^ ((c & 7) << 2))];
            }
            #pragma unroll
            for (int rr = 0; rr < 2; ++rr)
                #pragma unroll
                for (int cc = 0; cc < 2; ++cc)
                    acc[rr][cc] = fmaf(xv[rr].x, wv[cc].x, fmaf(xv[rr].y, wv[cc].y,
                                  fmaf(xv[rr].z, wv[cc].z, fmaf(xv[rr].w, wv[cc].w, acc[rr][cc]))));
        }
        if (m == 0) {
            #pragma unroll
            for (int rr = 0; rr < 2; ++rr)
                #pragma unroll
                for (int cc = 0; cc < 2; ++cc)
                    acc[rr][cc] = 1.f / (1.f + expf(-acc[rr][cc]));
            __syncthreads();                // Ws reads done -> bounce
            #pragma unroll
            for (int rr = 0; rr < 2; ++rr)
                #pragma unroll
                for (int cc = 0; cc < 2; ++cc)
                    Ws[(tr + 16 * rr) * 33 + tc + 16 * cc] = acc[rr][cc];
            __syncthreads();
            const int r = t >> 3, q = t & 7;
            float4 v;
            v.x = Ws[r * 33 + q * 4 + 0]; v.y = Ws[r * 33 + q * 4 + 1];
            v.z = Ws[r * 33 + q * 4 + 2]; v.w = Ws[r * 33 + q * 4 + 3];
            *(float4*)&QS[(size_t)(row0 + r) * DIMC + cg * 32 + q * 4] = v;
        } else if (m == 1) {
            #pragma unroll
            for (int rr = 0; rr < 2; ++rr) { kreg[rr][0] = acc[rr][0]; kreg[rr][1] = acc[rr][1]; }
        } else {
            #pragma unroll
            for (int rr = 0; rr < 2; ++rr) { vreg[rr][0] = acc[rr][0]; vreg[rr][1] = acc[rr][1]; }
        }
    }
    // EKV transform in registers: e = exp(k) (kmax/bmax cancel in num/den)
    const int b = row0 / NTOK;
    const int j0r = row0 - b * NTOK;
    float nu[2], de[2];
    #pragma unroll
    for (int cc = 0; cc < 2; ++cc) { nu[cc] = 0.f; de[cc] = 0.f; }
    #pragma unroll
    for (int rr = 0; rr < 2; ++rr) {
        const int j = j0r + tr + 16 * rr;
        #pragma unroll
        for (int cc = 0; cc < 2; ++cc) {
            const int h = cg * 2 + cc;      // col = cg*32 + tc + 16*cc -> h, d=tc
            const float e = expf(kreg[rr][cc]);
            const float nn = e * vreg[rr][cc];
            EKVt[((size_t)(h * DIMC + b * 32 + tc)) * NTOK + j] = f2bf(nn);
            EKVt[((size_t)(h * DIMC + b * 32 + 16 + tc)) * NTOK + j] = f2bf(e);
            nu[cc] += nn; de[cc] += e;
        }
    }
    #pragma unroll
    for (int s = 16; s <= 32; s <<= 1) {    // reduce over tr within wave
        #pragma unroll
        for (int cc = 0; cc < 2; ++cc) {
            nu[cc] += __shfl_xor(nu[cc], s, 64);
            de[cc] += __shfl_xor(de[cc], s, 64);
        }
    }
    if ((t & 48) == 0) {
        #pragma unroll
        for (int cc = 0; cc < 2; ++cc) {
            const int h = cg * 2 + cc;
            atomicAdd(&n1[(h * NB + b) * 32 + tc], nu[cc]);
            atomicAdd(&n1[(h * NB + b) * 32 + 16 + tc], de[cc]);
        }
    }
}

// ===== Kernel B: MFMA einsum (r4-proven), part[i][h][js][128] ===============
__global__ __launch_bounds__(256) void k_aft_mfma(
    const unsigned short* __restrict__ tblT,
    const unsigned short* __restrict__ EKVt,
    float* __restrict__ part)
{
    __shared__ __align__(16) unsigned short slds[2304];      // table window
    __shared__ __align__(16) unsigned short alds[64 * 64];   // w' tile, swizzled
    __shared__ __align__(16) unsigned short blds[128 * 64];  // ekv tile, swizzled
    const int t = threadIdx.x;
    const int i0 = blockIdx.x * 64;
    const int h = blockIdx.y;
    const int js = blockIdx.z;
    const int l = t & 63, w = t >> 6;
    const int il = l & 15, kg = l >> 4;

    const int j_base = js * 576;
    const int pj_lo = js * 4 * 529;
    const int pj_hi = pj_lo + 1851;
    const int idx_lo = Pdec(i0) + 6083 - pj_hi;
    {   // stage 2304 contiguous u16 (covers max window 2234)
        const unsigned short* src = &tblT[(size_t)h * TSTRIDE + idx_lo];
        #pragma unroll
        for (int p = 0; p < 9; ++p) slds[p * 256 + t] = src[p * 256 + t];
    }
    const int gi0 = w * 16;
    int qb[16];
    #pragma unroll
    for (int r = 0; r < 16; ++r) qb[r] = Pdec(i0 + gi0 + r) + 6083 - idx_lo;
    const int bc = t >> 3, bj8 = (t & 7) * 8;

    f32x4 acc[8];
    #pragma unroll
    for (int cf = 0; cf < 8; ++cf) acc[cf] = (f32x4){0.f, 0.f, 0.f, 0.f};

    for (int jt = 0; jt < 9; ++jt) {
        const int j0 = j_base + jt * 64;
        const int pj = Pdec(j0 + l);
        __syncthreads();
        #pragma unroll
        for (int p = 0; p < 4; ++p) {
            const int c = bc + p * 32;
            bf16x8 v = *(const bf16x8*)&EKVt[((size_t)h * DIMC + c) * NTOK + j0 + bj8];
            *(bf16x8*)&blds[c * 64 + (bj8 ^ ((c & 7) << 3))] = v;
        }
        #pragma unroll
        for (int r = 0; r < 16; ++r)
            alds[(gi0 + r) * 64 + (l ^ ((r & 7) << 3))] = slds[qb[r] - pj];
        __syncthreads();
        #pragma unroll
        for (int kk = 0; kk < 2; ++kk) {
            const int ia = w * 16 + il;
            const int ka = kk * 32 + kg * 8;
            bf16x8 af = *(const bf16x8*)&alds[ia * 64 + (ka ^ ((ia & 7) << 3))];
            #pragma unroll
            for (int cf = 0; cf < 8; ++cf) {
                const int cb = cf * 16 + il;
                bf16x8 bfv = *(const bf16x8*)&blds[cb * 64 + (ka ^ ((cb & 7) << 3))];
                acc[cf] = __builtin_amdgcn_mfma_f32_16x16x32_bf16(af, bfv, acc[cf], 0, 0, 0);
            }
        }
    }
    #pragma unroll
    for (int cf = 0; cf < 8; ++cf) {
        #pragma unroll
        for (int r = 0; r < 4; ++r) {
            const int i = i0 + w * 16 + kg * 4 + r;   // D: row=(l>>4)*4+reg
            const int c = cf * 16 + il;               //    col=l&15
            part[((size_t)(i * NHEAD + h) * 3 + js) * DIMC + c] = acc[cf][r];
        }
    }
}

// ===== Kernel C: reduce partials + finalize y + output projection ===========
// grid 432, block 256: 4 tokens/block (16 rows of (b,i)), all 128 out cols
__global__ __launch_bounds__(256) void k_reduce_out(
    const float* __restrict__ part, const float* __restrict__ n1,
    const float* __restrict__ QS, const float* __restrict__ Wp,
    const float* __restrict__ bp, float* __restrict__ out)
{
    __shared__ __align__(16) float ys[16 * 128];
    const int t = threadIdx.x;
    const int i0 = (int)blockIdx.x * 4;
    {   // reduce: thread = (hpair = t>>6, il = (t>>4)&3, b = (t>>2)&3, dq = t&3)
        const int hp = t >> 6, il = (t >> 4) & 3, b = (t >> 2) & 3, dq = t & 3;
        const int i = i0 + il;
        const int row = b * 4 + il;
        #pragma unroll
        for (int hh = 0; hh < 2; ++hh) {
            const int h = hp * 2 + hh;
            const float* pb = &part[((size_t)(i * NHEAD + h) * 3) * DIMC + b * 32 + dq * 4];
            float4 nu = *(const float4*)&n1[(h * NB + b) * 32 + dq * 4];
            float4 de = *(const float4*)&n1[(h * NB + b) * 32 + 16 + dq * 4];
            #pragma unroll
            for (int js = 0; js < 3; ++js) {
                float4 a = *(const float4*)&pb[js * DIMC];
                float4 d = *(const float4*)&pb[js * DIMC + 16];
                nu.x += a.x; nu.y += a.y; nu.z += a.z; nu.w += a.w;
                de.x += d.x; de.y += d.y; de.z += d.z; de.w += d.w;
            }
            float4 q = *(const float4*)&QS[((size_t)b * NTOK + i) * DIMC + h * 16 + dq * 4];
            float4 y;
            y.x = q.x * nu.x / de.x; y.y = q.y * nu.y / de.y;
            y.z = q.z * nu.z / de.z; y.w = q.w * nu.w / de.w;
            const int c4 = h * 4 + dq;      // 16B-unit column 0..31
            *(float4*)&ys[row * 128 + ((c4 * 4) ^ ((row & 7) << 2))] = y;
        }
    }
    __syncthreads();
    // proj: nl = t&15 -> row (b = nl>>2, tok = i0 + (nl&3)); wx = t>>4 -> 8 cols
    const int nl = t & 15, wx = t >> 4;
    float po[8];
    #pragma unroll
    for (int c = 0; c < 8; ++c) po[c] = 0.f;
    for (int k4 = 0; k4 < 32; ++k4) {
        const float4 xv = *(const float4*)&ys[nl * 128 + ((k4 * 4) ^ ((nl & 7) << 2))];
        #pragma unroll
        for (int c = 0; c < 8; ++c) {
            const float4 wv = *(const float4*)&Wp[(size_t)(wx * 8 + c) * DIMC + k4 * 4];
            po[c] = fmaf(xv.x, wv.x, fmaf(xv.y, wv.y,
                    fmaf(xv.z, wv.z, fmaf(xv.w, wv.w, po[c]))));
        }
    }
    const int b = nl >> 2, i = i0 + (nl & 3);
    const size_t ob = ((size_t)b * NTOK + i) * DIMC + wx * 8;
    float4 v0, v1;
    v0.x = po[0] + bp[wx * 8 + 0]; v0.y = po[1] + bp[wx * 8 + 1];
    v0.z = po[2] + bp[wx * 8 + 2]; v0.w = po[3] + bp[wx * 8 + 3];
    v1.x = po[4] + bp[wx * 8 + 4]; v1.y = po[5] + bp[wx * 8 + 5];
    v1.z = po[6] + bp[wx * 8 + 6]; v1.w = po[7] + bp[wx * 8 + 7];
    *(float4*)&out[ob] = v0;
    *(float4*)&out[ob + 4] = v1;
}

extern "C" void kernel_launch(void* const* d_in, const int* in_sizes, int n_in,
                              void* d_out, int out_size, void* d_ws, size_t ws_size,
                              hipStream_t stream) {
    const float* x    = (const float*)d_in[0];
    const float* Wq   = (const float*)d_in[1];
    const float* Wk   = (const float*)d_in[2];
    const float* Wv   = (const float*)d_in[3];
    const float* Wp   = (const float*)d_in[4];
    const float* bp   = (const float*)d_in[5];
    const float* tbl  = (const float*)d_in[6];

    float* ws = (float*)d_ws;
    float* n1 = ws;                                             // 1024 f32
    unsigned short* tblT = (unsigned short*)(ws + 1024);        // 97344 u16
    float* QS = ws + 1024 + 48672;                              // 884736 f32
    unsigned short* EKVt = (unsigned short*)(QS + 884736);      // 1769472 u16
    float* part = QS + 884736 + 884736;                         // 1728*8*3*128 f32

    hipMemsetAsync(n1, 0, 1024 * sizeof(float), stream);
    k_proj_ekv<<<dim3(1024), 256, 0, stream>>>(x, Wq, Wk, Wv, tbl, tblT, n1, QS, EKVt);
    k_aft_mfma<<<dim3(27, 8, 3), 256, 0, stream>>>(tblT, EKVt, part);
    k_reduce_out<<<dim3(432), 256, 0, stream>>>(part, n1, QS, Wp, bp, (float*)d_out);
}